// Round 2
// 1821.749 us; speedup vs baseline: 2.1737x; 2.1737x over previous
//
#include <hip/hip_runtime.h>
#include <hip/hip_bf16.h>
#include <math.h>

// ---------------- constants ----------------
#define Vv 32000
#define Dd 768
#define Ee 768
#define Hh 12
#define Bb 4
#define Ss 512
#define EPSf 1e-5f

typedef unsigned short u16;

struct __align__(8) us4 { u16 x, y, z, w; };

typedef __attribute__((ext_vector_type(8))) short bfrag;   // 8 bf16 (4 VGPRs)
typedef __attribute__((ext_vector_type(4))) float f32x4;   // 4 fp32 acc

__device__ __forceinline__ float b2f(u16 v) {
    union { unsigned u; float f; } x; x.u = ((unsigned)v) << 16; return x.f;
}
__device__ __forceinline__ u16 f2b(float f) {
    union { float f; unsigned u; } x; x.f = f;
    unsigned u = x.u;
    unsigned r = (u + 0x7FFFu + ((u >> 16) & 1u)) >> 16;
    return (u16)r;
}

__device__ __forceinline__ void load4(const float* p, float v[4]) {
    float4 q = *(const float4*)p; v[0]=q.x; v[1]=q.y; v[2]=q.z; v[3]=q.w;
}
__device__ __forceinline__ void load4(const u16* p, float v[4]) {
    us4 q = *(const us4*)p; v[0]=b2f(q.x); v[1]=b2f(q.y); v[2]=b2f(q.z); v[3]=b2f(q.w);
}
__device__ __forceinline__ void store1(float* p, float v) { *p = v; }
__device__ __forceinline__ void store1(u16* p, float v)   { *p = f2b(v); }

// ---------------- reductions ----------------
__device__ __forceinline__ float waveReduceSum(float v) {
    #pragma unroll
    for (int o = 32; o > 0; o >>= 1) v += __shfl_down(v, o, 64);
    return v;
}
__device__ __forceinline__ float waveReduceMax(float v) {
    #pragma unroll
    for (int o = 32; o > 0; o >>= 1) v = fmaxf(v, __shfl_down(v, o, 64));
    return v;
}
__device__ __forceinline__ float blockReduceSum(float v) {
    __shared__ float red[4];
    v = waveReduceSum(v);
    __syncthreads();
    if ((threadIdx.x & 63) == 0) red[threadIdx.x >> 6] = v;
    __syncthreads();
    return red[0] + red[1] + red[2] + red[3];
}
__device__ __forceinline__ float blockReduceMax(float v) {
    __shared__ float red[4];
    v = waveReduceMax(v);
    __syncthreads();
    if ((threadIdx.x & 63) == 0) red[threadIdx.x >> 6] = v;
    __syncthreads();
    return fmaxf(fmaxf(red[0], red[1]), fmaxf(red[2], red[3]));
}

__device__ __forceinline__ float gelu_exact(float x) {
    return 0.5f * x * (1.0f + erff(x * 0.70710678118654752f));
}

// ---------------- MFMA bf16 GEMM ----------------
// C[M,N] = alpha * A[M,K](bf16) @ (TB_T ? B[N,K]^T : B[K,N]) (+ bias)(+ gelu)
// 128x128 block tile, BK=32, 4 waves each computing a 64x64 sub-tile via
// v_mfma_f32_16x16x32_bf16 (A: lane%16=row, (lane/16)*8+i = k;
// B: lane%16=col, (lane/16)*8+i = k; C/D: col=lane&15, row=(lane>>4)*4+reg).
// batched over blockIdx.z: z0 = z % zmod, z1 = z / zmod

template<typename TB, typename TC, int EPI, bool TB_T>
__global__ __launch_bounds__(256)
void mfma_gemm(const u16* __restrict__ A, const TB* __restrict__ Bm,
               const float* __restrict__ bias, TC* __restrict__ C,
               int M, int N, int K, int lda, int ldb, int ldc, float alpha,
               int zmod,
               long long sA0, long long sA1, long long sB0, long long sB1,
               long long sC0, long long sC1, long long sb0, long long sb1)
{
    (void)M; (void)N;
    int z = blockIdx.z;
    int z0 = z % zmod, z1 = z / zmod;
    A  += (size_t)z0 * sA0 + (size_t)z1 * sA1;
    Bm += (size_t)z0 * sB0 + (size_t)z1 * sB1;
    C  += (size_t)z0 * sC0 + (size_t)z1 * sC1;
    if (bias) bias += (size_t)z0 * sb0 + (size_t)z1 * sb1;

    // +8 pad keeps 16B alignment (80B row stride) and spreads banks
    __shared__ u16 As[128][40];
    __shared__ u16 Bs[128][40];

    const int t    = threadIdx.x;
    const int lane = t & 63;
    const int wid  = t >> 6;
    const int wm   = (wid >> 1) * 64;   // wave row offset in tile
    const int wn   = (wid & 1) * 64;    // wave col offset in tile
    const int m0   = blockIdx.y * 128, n0 = blockIdx.x * 128;

    // A loader: each thread loads 16 contiguous bf16 (32B): row t>>1, k-chunk (t&1)*16
    const int ar = t >> 1, ak = (t & 1) * 16;
    // B K x N loader: row (k) = t>>3, 16 consecutive n at (t&7)*16
    const int bk = t >> 3, bn = (t & 7) * 16;

    f32x4 acc[4][4];
    #pragma unroll
    for (int mi = 0; mi < 4; mi++)
        #pragma unroll
        for (int ni = 0; ni < 4; ni++)
            acc[mi][ni] = (f32x4){0.f, 0.f, 0.f, 0.f};

    const int lrow = lane & 15;
    const int lk   = (lane >> 4) << 3;

    for (int kt = 0; kt < K; kt += 32) {
        // ---- global loads into regs (before barrier, hides latency) ----
        const u16* ap = A + (size_t)(m0 + ar) * lda + kt + ak;
        uint4 a0 = *(const uint4*)ap;
        uint4 a1 = *(const uint4*)(ap + 8);

        uint4 b0, b1;
        float bv[16];
        if constexpr (TB_T) {
            const u16* bp = (const u16*)Bm + (size_t)(n0 + ar) * ldb + kt + ak;
            b0 = *(const uint4*)bp;
            b1 = *(const uint4*)(bp + 8);
        } else {
            const TB* bp = Bm + (size_t)(kt + bk) * ldb + n0 + bn;
            #pragma unroll
            for (int c = 0; c < 4; c++) load4(bp + c * 4, &bv[c * 4]);
        }

        __syncthreads();   // previous tile fully consumed

        *(uint4*)&As[ar][ak]     = a0;
        *(uint4*)&As[ar][ak + 8] = a1;
        if constexpr (TB_T) {
            *(uint4*)&Bs[ar][ak]     = b0;
            *(uint4*)&Bs[ar][ak + 8] = b1;
        } else {
            // transpose K x N -> Bs[n][k], converting to bf16
            #pragma unroll
            for (int i = 0; i < 16; i++) Bs[bn + i][bk] = f2b(bv[i]);
        }

        __syncthreads();   // tile staged

        // ---- fragments + MFMA ----
        bfrag af[4], bfr[4];
        #pragma unroll
        for (int mi = 0; mi < 4; mi++)
            af[mi] = *(const bfrag*)&As[wm + mi * 16 + lrow][lk];
        #pragma unroll
        for (int ni = 0; ni < 4; ni++)
            bfr[ni] = *(const bfrag*)&Bs[wn + ni * 16 + lrow][lk];
        #pragma unroll
        for (int mi = 0; mi < 4; mi++)
            #pragma unroll
            for (int ni = 0; ni < 4; ni++)
                acc[mi][ni] = __builtin_amdgcn_mfma_f32_16x16x32_bf16(
                    af[mi], bfr[ni], acc[mi][ni], 0, 0, 0);
    }

    // ---- epilogue: C/D layout col=lane&15, row=(lane>>4)*4+i ----
    #pragma unroll
    for (int mi = 0; mi < 4; mi++) {
        int row = m0 + wm + mi * 16 + ((lane >> 4) << 2);
        #pragma unroll
        for (int ni = 0; ni < 4; ni++) {
            int col = n0 + wn + ni * 16 + (lane & 15);
            float bc = (EPI >= 1) ? bias[col] : 0.f;
            #pragma unroll
            for (int i = 0; i < 4; i++) {
                float v = acc[mi][ni][i] * alpha;
                if (EPI >= 1) v += bc;
                if (EPI == 2) v = gelu_exact(v);
                store1(C + (size_t)(row + i) * ldc + col, v);
            }
        }
    }
}

// ---------------- embed + LN (fp32 inputs -> bf16 X) ----------------
__global__ __launch_bounds__(256)
void embed_ln_kernel(const int* __restrict__ ids, const float* __restrict__ tok,
                     const float* __restrict__ seg, const float* __restrict__ g,
                     const float* __restrict__ be, u16* __restrict__ X)
{
    int r = blockIdx.x;            // r = b*S + s
    int s = r & (Ss - 1);
    int id = ids[r];
    int sg = (s >= Ss / 2 + 1) ? 1 : 0;
    float vals[3];
    #pragma unroll
    for (int c = 0; c < 3; c++) {
        int d = threadIdx.x + c * 256;
        float expo = -(2.0f * (float)d / (float)Dd) * 9.2103403719761836f; // ln(10000)
        float ang = (float)s * expf(expo);
        float pos = (d & 1) ? cosf(ang) : sinf(ang);
        vals[c] = tok[(size_t)id * Dd + d] + seg[(size_t)sg * Dd + d] + pos;
    }
    float sum = blockReduceSum(vals[0] + vals[1] + vals[2]);
    float mean = sum / (float)Dd;
    float vs = 0.f;
    #pragma unroll
    for (int c = 0; c < 3; c++) { float dlt = vals[c] - mean; vs += dlt * dlt; }
    vs = blockReduceSum(vs);
    float rstd = rsqrtf(vs / (float)Dd + EPSf);
    #pragma unroll
    for (int c = 0; c < 3; c++) {
        int d = threadIdx.x + c * 256;
        X[(size_t)r * Dd + d] = f2b((vals[c] - mean) * rstd * g[d] + be[d]);
    }
}

// ---------------- LN (fp32 src -> bf16 dst) ----------------
__global__ __launch_bounds__(256)
void ln_kernel(const float* __restrict__ src, const float* __restrict__ g,
               const float* __restrict__ be, u16* __restrict__ dst)
{
    int r = blockIdx.x;
    float vals[3];
    #pragma unroll
    for (int c = 0; c < 3; c++) vals[c] = src[(size_t)r * Dd + threadIdx.x + c * 256];
    float sum = blockReduceSum(vals[0] + vals[1] + vals[2]);
    float mean = sum / (float)Dd;
    float vs = 0.f;
    #pragma unroll
    for (int c = 0; c < 3; c++) { float dlt = vals[c] - mean; vs += dlt * dlt; }
    vs = blockReduceSum(vs);
    float rstd = rsqrtf(vs / (float)Dd + EPSf);
    #pragma unroll
    for (int c = 0; c < 3; c++) {
        int d = threadIdx.x + c * 256;
        dst[(size_t)r * Dd + d] = f2b((vals[c] - mean) * rstd * g[d] + be[d]);
    }
}

// ---------------- masked softmax over t (row len 512), in-place bf16 ----------------
__global__ __launch_bounds__(256)
void softmax_kernel(u16* __restrict__ scores, const unsigned char* __restrict__ mask)
{
    int row = blockIdx.x;          // row = (b*H + h)*S + s
    int z = row >> 9;              // b*H + h
    int s = row & (Ss - 1);
    int b = z / Hh;
    u16* sp = scores + (size_t)row * Ss;
    const unsigned char* mp = mask + ((size_t)(b * Ss + s)) * Ss;
    float v[2];
    #pragma unroll
    for (int c = 0; c < 2; c++) {
        int d = threadIdx.x + c * 256;
        v[c] = mp[d] ? -1e9f : b2f(sp[d]);
    }
    float mx = blockReduceMax(fmaxf(v[0], v[1]));
    float e[2]; e[0] = expf(v[0] - mx); e[1] = expf(v[1] - mx);
    float sum = blockReduceSum(e[0] + e[1]);
    float inv = 1.0f / sum;
    #pragma unroll
    for (int c = 0; c < 2; c++) {
        int d = threadIdx.x + c * 256;
        sp[d] = f2b(e[c] * inv);
    }
}

// ---------------- in-place log-softmax over V (fp32) ----------------
__global__ __launch_bounds__(256)
void logsoftmax_kernel(float* __restrict__ out)
{
    int row = blockIdx.x;
    size_t base = (size_t)row * Vv;
    float mx = -1e30f;
    for (int i = threadIdx.x; i < Vv; i += 256) mx = fmaxf(mx, out[base + i]);
    mx = blockReduceMax(mx);
    float s = 0.f;
    for (int i = threadIdx.x; i < Vv; i += 256) s += expf(out[base + i] - mx);
    s = blockReduceSum(s);
    float lse = logf(s);
    for (int i = threadIdx.x; i < Vv; i += 256) {
        out[base + i] = out[base + i] - mx - lse;
    }
}

// ---------------- cls head (fp32 out) ----------------
__global__ __launch_bounds__(64)
void cls_kernel(const u16* __restrict__ enc, const float* __restrict__ Wc,
                const float* __restrict__ bc, float* __restrict__ out)
{
    int idx = blockIdx.x;          // 0..7 : b*2 + j
    int b = idx >> 1, j = idx & 1;
    float s = 0.f;
    for (int d = threadIdx.x; d < Dd; d += 64)
        s += b2f(enc[((size_t)b * Ss) * Dd + d]) * Wc[d * 2 + j];
    s = waveReduceSum(s);
    if (threadIdx.x == 0)
        out[(size_t)Bb * Ss * Vv + idx] = s + bc[j];
}

// ---------------- launch ----------------
extern "C" void kernel_launch(void* const* d_in, const int* in_sizes, int n_in,
                              void* d_out, int out_size, void* d_ws, size_t ws_size,
                              hipStream_t stream)
{
    const int* ids            = (const int*)d_in[0];
    const unsigned char* mask = (const unsigned char*)d_in[1];
    const float* tok   = (const float*)d_in[2];
    const float* seg   = (const float*)d_in[3];
    const float* g_emb = (const float*)d_in[4];
    const float* b_emb = (const float*)d_in[5];
    const float* Wq    = (const float*)d_in[6];
    const float* bq    = (const float*)d_in[7];
    const float* Wk    = (const float*)d_in[8];
    const float* bk    = (const float*)d_in[9];
    const float* Wv    = (const float*)d_in[10];
    const float* bv    = (const float*)d_in[11];
    const float* Wo    = (const float*)d_in[12];
    const float* bo    = (const float*)d_in[13];
    const float* g_at  = (const float*)d_in[14];
    const float* b_at  = (const float*)d_in[15];
    const float* W1    = (const float*)d_in[16];
    const float* b1    = (const float*)d_in[17];
    const float* W2    = (const float*)d_in[18];
    const float* b2    = (const float*)d_in[19];
    const float* g_ff  = (const float*)d_in[20];
    const float* b_ff  = (const float*)d_in[21];
    const float* Wp    = (const float*)d_in[22];
    const float* bp    = (const float*)d_in[23];
    const float* Wc    = (const float*)d_in[24];
    const float* bc    = (const float*)d_in[25];

    char* ws = (char*)d_ws;
    size_t off = 0;
    auto alloc = [&](size_t bytes) { void* p = ws + off; off += (bytes + 255) & ~(size_t)255; return p; };

    u16*   X      = (u16*)  alloc((size_t)Bb*Ss*Dd*2);           // 3.1 MB
    u16*   q      = (u16*)  alloc((size_t)Bb*Hh*Ss*Ee*2);        // 37.7 MB
    u16*   k      = (u16*)  alloc((size_t)Bb*Hh*Ss*Ee*2);
    u16*   v      = (u16*)  alloc((size_t)Bb*Hh*Ss*Ee*2);
    u16*   sc     = (u16*)  alloc((size_t)Bb*Hh*Ss*Ss*2);        // 25.2 MB (scores, softmaxed in-place)
    u16*   ctxc   = (u16*)  alloc((size_t)Bb*Ss*Hh*Ee*2);        // 37.7 MB
    float* t1     = (float*)alloc((size_t)Bb*Ss*Dd*4);           // 6.3 MB
    u16*   attn_o = (u16*)  alloc((size_t)Bb*Ss*Dd*2);
    u16*   h1     = (u16*)  alloc((size_t)Bb*Ss*Dd*2);
    float* t2     = (float*)alloc((size_t)Bb*Ss*Dd*4);
    u16*   enc    = (u16*)  alloc((size_t)Bb*Ss*Dd*2);
    (void)ws_size; (void)in_sizes; (void)n_in; (void)out_size;

    float* outp = (float*)d_out;   // fp32 output: [B*S, V] log-softmax + 8 cls floats

    // 1. embedding + LN -> X (bf16)
    embed_ln_kernel<<<Bb*Ss, 256, 0, stream>>>(ids, tok, seg, g_emb, b_emb, X);

    // 2. QKV projections: per (b,h): [512,768] @ [768,768] + bias
    const long long SD = (long long)Ss*Dd, DE = (long long)Dd*Ee, SE = (long long)Ss*Ee;
    dim3 gqkv(Ee/128, Ss/128, Bb*Hh);
    mfma_gemm<float,u16,1,false><<<gqkv, 256, 0, stream>>>(
        X, Wq, bq, q, Ss, Ee, Dd, Dd, Ee, Ee, 1.0f,
        Bb, SD, 0, 0, DE, (long long)Hh*SE, SE, 0, Ee);
    mfma_gemm<float,u16,1,false><<<gqkv, 256, 0, stream>>>(
        X, Wk, bk, k, Ss, Ee, Dd, Dd, Ee, Ee, 1.0f,
        Bb, SD, 0, 0, DE, (long long)Hh*SE, SE, 0, Ee);
    mfma_gemm<float,u16,1,false><<<gqkv, 256, 0, stream>>>(
        X, Wv, bv, v, Ss, Ee, Dd, Dd, Ee, Ee, 1.0f,
        Bb, SD, 0, 0, DE, (long long)Hh*SE, SE, 0, Ee);

    // 3. scores = q @ k^T / sqrt(S)  (NT GEMM, bf16 out)
    dim3 gsc(Ss/128, Ss/128, Bb*Hh);
    mfma_gemm<u16,u16,0,true><<<gsc, 256, 0, stream>>>(
        q, k, nullptr, sc, Ss, Ss, Ee, Ee, Ee, Ss, 0.044194173824159216f,
        1, 0, SE, 0, SE, 0, (long long)Ss*Ss, 0, 0);

    // 4. mask + softmax in-place on sc (bf16)
    softmax_kernel<<<Bb*Hh*Ss, 256, 0, stream>>>(sc, mask);

    // 5. ctx = attn @ v, written concat-transposed: ctxc[b, s, h*E+e]
    dim3 gctx(Ee/128, Ss/128, Bb*Hh);
    mfma_gemm<u16,u16,0,false><<<gctx, 256, 0, stream>>>(
        sc, v, nullptr, ctxc, Ss, Ee, Ss, Ss, Ee, Hh*Ee, 1.0f,
        Hh, (long long)Ss*Ss, (long long)Hh*Ss*Ss, SE, (long long)Hh*SE,
        Ee, (long long)Ss*Hh*Ee, 0, 0);

    // 6. t1 = ctxc @ Wo + bo (fp32) ; LN -> attn_o
    dim3 gwo(Dd/128, (Bb*Ss)/128, 1);
    mfma_gemm<float,float,1,false><<<gwo, 256, 0, stream>>>(
        ctxc, Wo, bo, t1, Bb*Ss, Dd, Hh*Ee, Hh*Ee, Dd, Dd, 1.0f,
        1, 0,0,0,0,0,0,0,0);
    ln_kernel<<<Bb*Ss, 256, 0, stream>>>(t1, g_at, b_at, attn_o);

    // 7. h1 = gelu(attn_o @ W1 + b1) (bf16)
    mfma_gemm<float,u16,2,false><<<gwo, 256, 0, stream>>>(
        attn_o, W1, b1, h1, Bb*Ss, Ee, Dd, Dd, Ee, Ee, 1.0f,
        1, 0,0,0,0,0,0,0,0);

    // 8. t2 = h1 @ W2 + b2 (fp32) ; LN -> enc
    mfma_gemm<float,float,1,false><<<gwo, 256, 0, stream>>>(
        h1, W2, b2, t2, Bb*Ss, Dd, Ee, Ee, Dd, Dd, 1.0f,
        1, 0,0,0,0,0,0,0,0);
    ln_kernel<<<Bb*Ss, 256, 0, stream>>>(t2, g_ff, b_ff, enc);

    // 9. logits = enc @ Wp + bp -> d_out (fp32), then in-place log-softmax
    dim3 gwp(Vv/128, (Bb*Ss)/128, 1);
    mfma_gemm<float,float,1,false><<<gwp, 256, 0, stream>>>(
        enc, Wp, bp, outp, Bb*Ss, Vv, Dd, Dd, Vv, Vv, 1.0f,
        1, 0,0,0,0,0,0,0,0);
    logsoftmax_kernel<<<Bb*Ss, 256, 0, stream>>>(outp);

    // 10. cls head -> last 8 outputs (fp32)
    cls_kernel<<<Bb*2, 64, 0, stream>>>(enc, Wc, bc, outp);
}

// Round 3
// 1338.095 us; speedup vs baseline: 2.9594x; 1.3614x over previous
//
#include <hip/hip_runtime.h>
#include <hip/hip_bf16.h>
#include <math.h>

// ---------------- constants ----------------
#define Vv 32000
#define Dd 768
#define Ee 768
#define Hh 12
#define Bb 4
#define Ss 512
#define EPSf 1e-5f

typedef unsigned short u16;

struct __align__(8) us4 { u16 x, y, z, w; };

typedef __attribute__((ext_vector_type(8))) short bfrag;   // 8 bf16 (4 VGPRs)
typedef __attribute__((ext_vector_type(4))) float f32x4;   // 4 fp32 acc

__device__ __forceinline__ float b2f(u16 v) {
    union { unsigned u; float f; } x; x.u = ((unsigned)v) << 16; return x.f;
}
__device__ __forceinline__ u16 f2b(float f) {
    union { float f; unsigned u; } x; x.f = f;
    unsigned u = x.u;
    unsigned r = (u + 0x7FFFu + ((u >> 16) & 1u)) >> 16;
    return (u16)r;
}

__device__ __forceinline__ void load4(const float* p, float v[4]) {
    float4 q = *(const float4*)p; v[0]=q.x; v[1]=q.y; v[2]=q.z; v[3]=q.w;
}
__device__ __forceinline__ void load4(const u16* p, float v[4]) {
    us4 q = *(const us4*)p; v[0]=b2f(q.x); v[1]=b2f(q.y); v[2]=b2f(q.z); v[3]=b2f(q.w);
}
__device__ __forceinline__ void store1(float* p, float v) { *p = v; }
__device__ __forceinline__ void store1(u16* p, float v)   { *p = f2b(v); }

// ---------------- reductions ----------------
__device__ __forceinline__ float waveReduceSum(float v) {
    #pragma unroll
    for (int o = 32; o > 0; o >>= 1) v += __shfl_down(v, o, 64);
    return v;
}
__device__ __forceinline__ float waveReduceMax(float v) {
    #pragma unroll
    for (int o = 32; o > 0; o >>= 1) v = fmaxf(v, __shfl_down(v, o, 64));
    return v;
}
__device__ __forceinline__ float blockReduceSum(float v) {
    __shared__ float red[4];
    v = waveReduceSum(v);
    __syncthreads();
    if ((threadIdx.x & 63) == 0) red[threadIdx.x >> 6] = v;
    __syncthreads();
    return red[0] + red[1] + red[2] + red[3];
}
__device__ __forceinline__ float blockReduceMax(float v) {
    __shared__ float red[4];
    v = waveReduceMax(v);
    __syncthreads();
    if ((threadIdx.x & 63) == 0) red[threadIdx.x >> 6] = v;
    __syncthreads();
    return fmaxf(fmaxf(red[0], red[1]), fmaxf(red[2], red[3]));
}

__device__ __forceinline__ float gelu_exact(float x) {
    return 0.5f * x * (1.0f + erff(x * 0.70710678118654752f));
}

// ---------------- weight transpose: in[K][N] fp32 -> out[N][K] bf16 ----------------
__global__ __launch_bounds__(256)
void transpose_w(const float* __restrict__ in, u16* __restrict__ out, int K, int N)
{
    __shared__ float tile[64][65];
    int k0 = blockIdx.y * 64, n0 = blockIdx.x * 64;
    int tx = threadIdx.x & 15, ty = threadIdx.x >> 4;
    #pragma unroll
    for (int i = 0; i < 4; i++) {
        int kk = ty + i * 16;
        float4 q = *(const float4*)&in[(size_t)(k0 + kk) * N + n0 + tx * 4];
        tile[kk][tx * 4 + 0] = q.x; tile[kk][tx * 4 + 1] = q.y;
        tile[kk][tx * 4 + 2] = q.z; tile[kk][tx * 4 + 3] = q.w;
    }
    __syncthreads();
    #pragma unroll
    for (int i = 0; i < 4; i++) {
        int n = ty + i * 16;
        us4 o;
        o.x = f2b(tile[tx * 4 + 0][n]);
        o.y = f2b(tile[tx * 4 + 1][n]);
        o.z = f2b(tile[tx * 4 + 2][n]);
        o.w = f2b(tile[tx * 4 + 3][n]);
        *(us4*)&out[(size_t)(n0 + n) * K + k0 + tx * 4] = o;
    }
}

// ---------------- MFMA bf16 GEMM ----------------
// C[M,N] = alpha * A[M,K](bf16) @ (TB_T ? B[N,K]^T : B[K,N]) (+ bias)(+ gelu)
// 128x128 block tile, BK=32, 4 waves each computing a 64x64 sub-tile via
// v_mfma_f32_16x16x32_bf16. C/D frag: col=lane&15, row=(lane>>4)*4+reg.
// CT: store transposed, C[col*ldc + row] (only instantiated with TC=u16).
// batched over blockIdx.z: z0 = z % zmod, z1 = z / zmod

template<typename TB, typename TC, int EPI, bool TB_T, bool CT>
__global__ __launch_bounds__(256)
void mfma_gemm(const u16* __restrict__ A, const TB* __restrict__ Bm,
               const float* __restrict__ bias, TC* __restrict__ C,
               int M, int N, int K, int lda, int ldb, int ldc, float alpha,
               int zmod,
               long long sA0, long long sA1, long long sB0, long long sB1,
               long long sC0, long long sC1, long long sb0, long long sb1)
{
    (void)M; (void)N;
    int z = blockIdx.z;
    int z0 = z % zmod, z1 = z / zmod;
    A  += (size_t)z0 * sA0 + (size_t)z1 * sA1;
    Bm += (size_t)z0 * sB0 + (size_t)z1 * sB1;
    C  += (size_t)z0 * sC0 + (size_t)z1 * sC1;
    if (bias) bias += (size_t)z0 * sb0 + (size_t)z1 * sb1;

    // +8 pad keeps 16B alignment (80B row stride) and spreads banks
    __shared__ u16 As[128][40];
    __shared__ u16 Bs[128][40];

    const int t    = threadIdx.x;
    const int lane = t & 63;
    const int wid  = t >> 6;
    const int wm   = (wid >> 1) * 64;   // wave row offset in tile
    const int wn   = (wid & 1) * 64;    // wave col offset in tile
    const int m0   = blockIdx.y * 128, n0 = blockIdx.x * 128;

    // A loader: each thread loads 16 contiguous bf16 (32B): row t>>1, k-chunk (t&1)*16
    const int ar = t >> 1, ak = (t & 1) * 16;
    // B K x N loader (NN path): k-row = t>>3, 16 consecutive n at (t&7)*16
    const int bk = t >> 3, bn = (t & 7) * 16;

    f32x4 acc[4][4];
    #pragma unroll
    for (int mi = 0; mi < 4; mi++)
        #pragma unroll
        for (int ni = 0; ni < 4; ni++)
            acc[mi][ni] = (f32x4){0.f, 0.f, 0.f, 0.f};

    const int lrow = lane & 15;
    const int lk   = (lane >> 4) << 3;

    for (int kt = 0; kt < K; kt += 32) {
        // ---- global loads into regs (before barrier, hides latency) ----
        const u16* ap = A + (size_t)(m0 + ar) * lda + kt + ak;
        uint4 a0 = *(const uint4*)ap;
        uint4 a1 = *(const uint4*)(ap + 8);

        uint4 b0, b1;
        float bv[16];
        if constexpr (TB_T) {
            const u16* bp = (const u16*)Bm + (size_t)(n0 + ar) * ldb + kt + ak;
            b0 = *(const uint4*)bp;
            b1 = *(const uint4*)(bp + 8);
        } else {
            const TB* bp = Bm + (size_t)(kt + bk) * ldb + n0 + bn;
            #pragma unroll
            for (int c = 0; c < 4; c++) load4(bp + c * 4, &bv[c * 4]);
        }

        __syncthreads();   // previous tile fully consumed

        *(uint4*)&As[ar][ak]     = a0;
        *(uint4*)&As[ar][ak + 8] = a1;
        if constexpr (TB_T) {
            *(uint4*)&Bs[ar][ak]     = b0;
            *(uint4*)&Bs[ar][ak + 8] = b1;
        } else {
            // transpose K x N -> Bs[n][k], converting to bf16
            #pragma unroll
            for (int i = 0; i < 16; i++) Bs[bn + i][bk] = f2b(bv[i]);
        }

        __syncthreads();   // tile staged

        // ---- fragments + MFMA ----
        bfrag af[4], bfr[4];
        #pragma unroll
        for (int mi = 0; mi < 4; mi++)
            af[mi] = *(const bfrag*)&As[wm + mi * 16 + lrow][lk];
        #pragma unroll
        for (int ni = 0; ni < 4; ni++)
            bfr[ni] = *(const bfrag*)&Bs[wn + ni * 16 + lrow][lk];
        #pragma unroll
        for (int mi = 0; mi < 4; mi++)
            #pragma unroll
            for (int ni = 0; ni < 4; ni++)
                acc[mi][ni] = __builtin_amdgcn_mfma_f32_16x16x32_bf16(
                    af[mi], bfr[ni], acc[mi][ni], 0, 0, 0);
    }

    // ---- epilogue: C/D layout col=lane&15, row=(lane>>4)*4+i ----
    #pragma unroll
    for (int mi = 0; mi < 4; mi++) {
        int row = m0 + wm + mi * 16 + ((lane >> 4) << 2);
        #pragma unroll
        for (int ni = 0; ni < 4; ni++) {
            int col = n0 + wn + ni * 16 + (lane & 15);
            float bc = (EPI >= 1) ? bias[col] : 0.f;
            if constexpr (CT) {
                // transposed store: 4 consecutive rows at fixed col -> 8B store
                us4 o;
                float v0 = acc[mi][ni][0] * alpha + bc;
                float v1 = acc[mi][ni][1] * alpha + bc;
                float v2 = acc[mi][ni][2] * alpha + bc;
                float v3 = acc[mi][ni][3] * alpha + bc;
                o.x = f2b(v0); o.y = f2b(v1); o.z = f2b(v2); o.w = f2b(v3);
                *(us4*)&C[(size_t)col * ldc + row] = o;
            } else {
                #pragma unroll
                for (int i = 0; i < 4; i++) {
                    float v = acc[mi][ni][i] * alpha;
                    if (EPI >= 1) v += bc;
                    if (EPI == 2) v = gelu_exact(v);
                    store1(C + (size_t)(row + i) * ldc + col, v);
                }
            }
        }
    }
}

// ---------------- split-K reducer + epilogue ----------------
// MODE 0: sum partials + bias, LayerNorm(g,be) -> bf16
// MODE 1: sum partials + bias, GELU -> bf16
template<int NS, int MODE>
__global__ __launch_bounds__(256)
void reduce_ep(const float* __restrict__ src, const float* __restrict__ bias,
               const float* __restrict__ g, const float* __restrict__ be,
               u16* __restrict__ dst)
{
    const long long SLAB = (long long)Bb * Ss * Dd;
    int r = blockIdx.x;
    float vals[3];
    #pragma unroll
    for (int c = 0; c < 3; c++) {
        int d = threadIdx.x + c * 256;
        float s = bias[d];
        #pragma unroll
        for (int n = 0; n < NS; n++)
            s += src[(size_t)n * SLAB + (size_t)r * Dd + d];
        vals[c] = s;
    }
    if (MODE == 1) {
        #pragma unroll
        for (int c = 0; c < 3; c++) {
            int d = threadIdx.x + c * 256;
            dst[(size_t)r * Dd + d] = f2b(gelu_exact(vals[c]));
        }
        return;
    }
    float sum = blockReduceSum(vals[0] + vals[1] + vals[2]);
    float mean = sum / (float)Dd;
    float vs = 0.f;
    #pragma unroll
    for (int c = 0; c < 3; c++) { float dlt = vals[c] - mean; vs += dlt * dlt; }
    vs = blockReduceSum(vs);
    float rstd = rsqrtf(vs / (float)Dd + EPSf);
    #pragma unroll
    for (int c = 0; c < 3; c++) {
        int d = threadIdx.x + c * 256;
        dst[(size_t)r * Dd + d] = f2b((vals[c] - mean) * rstd * g[d] + be[d]);
    }
}

// ---------------- embed + LN (fp32 inputs -> bf16 X) ----------------
__global__ __launch_bounds__(256)
void embed_ln_kernel(const int* __restrict__ ids, const float* __restrict__ tok,
                     const float* __restrict__ seg, const float* __restrict__ g,
                     const float* __restrict__ be, u16* __restrict__ X)
{
    int r = blockIdx.x;            // r = b*S + s
    int s = r & (Ss - 1);
    int id = ids[r];
    int sg = (s >= Ss / 2 + 1) ? 1 : 0;
    float vals[3];
    #pragma unroll
    for (int c = 0; c < 3; c++) {
        int d = threadIdx.x + c * 256;
        float expo = -(2.0f * (float)d / (float)Dd) * 9.2103403719761836f; // ln(10000)
        float ang = (float)s * expf(expo);
        float pos = (d & 1) ? cosf(ang) : sinf(ang);
        vals[c] = tok[(size_t)id * Dd + d] + seg[(size_t)sg * Dd + d] + pos;
    }
    float sum = blockReduceSum(vals[0] + vals[1] + vals[2]);
    float mean = sum / (float)Dd;
    float vs = 0.f;
    #pragma unroll
    for (int c = 0; c < 3; c++) { float dlt = vals[c] - mean; vs += dlt * dlt; }
    vs = blockReduceSum(vs);
    float rstd = rsqrtf(vs / (float)Dd + EPSf);
    #pragma unroll
    for (int c = 0; c < 3; c++) {
        int d = threadIdx.x + c * 256;
        X[(size_t)r * Dd + d] = f2b((vals[c] - mean) * rstd * g[d] + be[d]);
    }
}

// ---------------- masked softmax over t (row len 512), in-place bf16 ----------------
__global__ __launch_bounds__(256)
void softmax_kernel(u16* __restrict__ scores, const unsigned char* __restrict__ mask)
{
    int row = blockIdx.x;          // row = (b*H + h)*S + s
    int z = row >> 9;              // b*H + h
    int s = row & (Ss - 1);
    int b = z / Hh;
    u16* sp = scores + (size_t)row * Ss;
    const unsigned char* mp = mask + ((size_t)(b * Ss + s)) * Ss;
    float v[2];
    #pragma unroll
    for (int c = 0; c < 2; c++) {
        int d = threadIdx.x + c * 256;
        v[c] = mp[d] ? -1e9f : b2f(sp[d]);
    }
    float mx = blockReduceMax(fmaxf(v[0], v[1]));
    float e[2]; e[0] = expf(v[0] - mx); e[1] = expf(v[1] - mx);
    float sum = blockReduceSum(e[0] + e[1]);
    float inv = 1.0f / sum;
    #pragma unroll
    for (int c = 0; c < 2; c++) {
        int d = threadIdx.x + c * 256;
        sp[d] = f2b(e[c] * inv);
    }
}

// ---------------- in-place log-softmax over V (fp32), online max+sum ----------------
__global__ __launch_bounds__(256)
void logsoftmax_kernel(float* __restrict__ out)
{
    int row = blockIdx.x;
    size_t base = (size_t)row * Vv;
    float m = -1e30f, l = 0.f;
    for (int i = threadIdx.x; i < Vv; i += 256) {
        float x = out[base + i];
        if (x > m) { l = l * expf(m - x) + 1.f; m = x; }
        else       { l += expf(x - m); }
    }
    float mx = blockReduceMax(m);
    l *= expf(m - mx);
    float s = blockReduceSum(l);
    float lse = mx + logf(s);
    for (int i = threadIdx.x; i < Vv; i += 256)
        out[base + i] -= lse;
}

// ---------------- cls head (fp32 out) ----------------
__global__ __launch_bounds__(64)
void cls_kernel(const u16* __restrict__ enc, const float* __restrict__ Wc,
                const float* __restrict__ bc, float* __restrict__ out)
{
    int idx = blockIdx.x;          // 0..7 : b*2 + j
    int b = idx >> 1, j = idx & 1;
    float s = 0.f;
    for (int d = threadIdx.x; d < Dd; d += 64)
        s += b2f(enc[((size_t)b * Ss) * Dd + d]) * Wc[d * 2 + j];
    s = waveReduceSum(s);
    if (threadIdx.x == 0)
        out[(size_t)Bb * Ss * Vv + idx] = s + bc[j];
}

// ---------------- launch ----------------
extern "C" void kernel_launch(void* const* d_in, const int* in_sizes, int n_in,
                              void* d_out, int out_size, void* d_ws, size_t ws_size,
                              hipStream_t stream)
{
    const int* ids            = (const int*)d_in[0];
    const unsigned char* mask = (const unsigned char*)d_in[1];
    const float* tok   = (const float*)d_in[2];
    const float* seg   = (const float*)d_in[3];
    const float* g_emb = (const float*)d_in[4];
    const float* b_emb = (const float*)d_in[5];
    const float* Wq    = (const float*)d_in[6];
    const float* bq    = (const float*)d_in[7];
    const float* Wk    = (const float*)d_in[8];
    const float* bk    = (const float*)d_in[9];
    const float* Wv    = (const float*)d_in[10];
    const float* bv    = (const float*)d_in[11];
    const float* Wo    = (const float*)d_in[12];
    const float* bo    = (const float*)d_in[13];
    const float* g_at  = (const float*)d_in[14];
    const float* b_at  = (const float*)d_in[15];
    const float* W1    = (const float*)d_in[16];
    const float* b1    = (const float*)d_in[17];
    const float* W2    = (const float*)d_in[18];
    const float* b2    = (const float*)d_in[19];
    const float* g_ff  = (const float*)d_in[20];
    const float* b_ff  = (const float*)d_in[21];
    const float* Wp    = (const float*)d_in[22];
    const float* bp    = (const float*)d_in[23];
    const float* Wc    = (const float*)d_in[24];
    const float* bc    = (const float*)d_in[25];

    char* ws = (char*)d_ws;
    size_t off = 0;
    auto alloc = [&](size_t bytes) { void* p = ws + off; off += (bytes + 255) & ~(size_t)255; return p; };

    u16*   X      = (u16*)  alloc((size_t)Bb*Ss*Dd*2);           // 3.1 MB
    size_t q_off  = off;
    u16*   q      = (u16*)  alloc((size_t)Bb*Hh*Ss*Ee*2);        // 37.7 MB (dead after scores)
    u16*   k      = (u16*)  alloc((size_t)Bb*Hh*Ss*Ee*2);        // 37.7 MB (dead after scores)
    u16*   vT     = (u16*)  alloc((size_t)Bb*Hh*Ss*Ee*2);        // 37.7 MB: vT[b][h][e][s]
    size_t sc_off = off;
    u16*   sc     = (u16*)  alloc((size_t)Bb*Hh*Ss*Ss*2);        // 25.2 MB (dead after ctx)
    u16*   ctxc   = (u16*)  alloc((size_t)Bb*Ss*Hh*Ee*2);        // 37.7 MB (dead after Wo gemm)
    u16*   attn_o = (u16*)  alloc((size_t)Bb*Ss*Dd*2);
    u16*   h1     = (u16*)  alloc((size_t)Bb*Ss*Dd*2);
    u16*   enc    = (u16*)  alloc((size_t)Bb*Ss*Dd*2);
    u16*   W1T    = (u16*)  alloc((size_t)Dd*Ee*2);              // 1.2 MB
    u16*   W2T    = (u16*)  alloc((size_t)Ee*Dd*2);              // 1.2 MB
    // Aliased regions (lifetimes verified):
    //  part: split-K partials, max 8 slabs of [2048][768] f32 = 50.3 MB over q+k (dead after scores)
    float* part = (float*)(ws + q_off);
    //  WoT: [768][9216] bf16 = 14.2 MB at q_off+50.3MB (inside q+k's 75.5 MB), written after scores
    u16*   WoT  = (u16*)(ws + q_off + (size_t)8*Bb*Ss*Dd*4);
    //  WpT: [32000][768] bf16 = 49.2 MB over sc+ctxc (62.9 MB, dead after Wo gemm)
    u16*   WpT  = (u16*)(ws + sc_off);
    (void)ws_size; (void)in_sizes; (void)n_in; (void)out_size;

    float* outp = (float*)d_out;   // fp32 output: [B*S, V] log-softmax + 8 cls floats

    const long long SD = (long long)Ss*Dd, DE = (long long)Dd*Ee, SE = (long long)Ss*Ee;
    const long long MD = (long long)Bb*Ss*Dd;   // partial slab stride (elements)

    // 1. embedding + LN -> X (bf16); small weight transposes
    embed_ln_kernel<<<Bb*Ss, 256, 0, stream>>>(ids, tok, seg, g_emb, b_emb, X);
    transpose_w<<<dim3(Ee/64, Dd/64), 256, 0, stream>>>(W1, W1T, Dd, Ee);
    transpose_w<<<dim3(Dd/64, Ee/64), 256, 0, stream>>>(W2, W2T, Ee, Dd);

    // 2. QKV projections: per (b,h): [512,768] @ [768,768] + bias; V stored transposed
    dim3 gqkv(Ee/128, Ss/128, Bb*Hh);
    mfma_gemm<float,u16,1,false,false><<<gqkv, 256, 0, stream>>>(
        X, Wq, bq, q, Ss, Ee, Dd, Dd, Ee, Ee, 1.0f,
        Bb, SD, 0, 0, DE, (long long)Hh*SE, SE, 0, Ee);
    mfma_gemm<float,u16,1,false,false><<<gqkv, 256, 0, stream>>>(
        X, Wk, bk, k, Ss, Ee, Dd, Dd, Ee, Ee, 1.0f,
        Bb, SD, 0, 0, DE, (long long)Hh*SE, SE, 0, Ee);
    mfma_gemm<float,u16,1,false,true><<<gqkv, 256, 0, stream>>>(
        X, Wv, bv, vT, Ss, Ee, Dd, Dd, Ee, /*ldc=*/Ss, 1.0f,
        Bb, SD, 0, 0, DE, (long long)Hh*SE, SE, 0, Ee);

    // 3. scores = q @ k^T / sqrt(S)  (NT GEMM, bf16 out)
    dim3 gsc(Ss/128, Ss/128, Bb*Hh);
    mfma_gemm<u16,u16,0,true,false><<<gsc, 256, 0, stream>>>(
        q, k, nullptr, sc, Ss, Ss, Ee, Ee, Ee, Ss, 0.044194173824159216f,
        1, 0, SE, 0, SE, 0, (long long)Ss*Ss, 0, 0);

    // q,k dead now: transpose Wo into the aliased region
    transpose_w<<<dim3(Dd/64, (Hh*Ee)/64), 256, 0, stream>>>(Wo, WoT, Hh*Ee, Dd);

    // 4. mask + softmax in-place on sc (bf16)
    softmax_kernel<<<Bb*Hh*Ss, 256, 0, stream>>>(sc, mask);

    // 5. ctx = attn @ v via vT (NT path), written concat: ctxc[b, s, h*E+e]
    dim3 gctx(Ee/128, Ss/128, Bb*Hh);
    mfma_gemm<u16,u16,0,true,false><<<gctx, 256, 0, stream>>>(
        sc, vT, nullptr, ctxc, Ss, Ee, Ss, Ss, /*ldb=*/Ss, Hh*Ee, 1.0f,
        Hh, (long long)Ss*Ss, (long long)Hh*Ss*Ss, SE, (long long)Hh*SE,
        Ee, (long long)Ss*Hh*Ee, 0, 0);

    // 6. Wo projection, split-K 8-way: part[ks] = ctxc @ WoT[ks-slice]
    mfma_gemm<u16,float,0,true,false><<<dim3(Dd/128, (Bb*Ss)/128, 8), 256, 0, stream>>>(
        ctxc, WoT, nullptr, part, Bb*Ss, Dd, /*Kc=*/1152, Hh*Ee, Hh*Ee, Dd, 1.0f,
        1, 0, 1152, 0, 1152, 0, MD, 0, 0);

    // sc,ctxc dead now: transpose Wp into the aliased region
    transpose_w<<<dim3(Vv/64, Dd/64), 256, 0, stream>>>(Wp, WpT, Dd, Vv);

    // reduce partials + bo, LN -> attn_o
    reduce_ep<8,0><<<Bb*Ss, 256, 0, stream>>>(part, bo, g_at, b_at, attn_o);

    // 7. h1 = gelu(attn_o @ W1 + b1), split-K 4-way
    mfma_gemm<u16,float,0,true,false><<<dim3(Ee/128, (Bb*Ss)/128, 4), 256, 0, stream>>>(
        attn_o, W1T, nullptr, part, Bb*Ss, Ee, /*Kc=*/192, Dd, Dd, Ee, 1.0f,
        1, 0, 192, 0, 192, 0, MD, 0, 0);
    reduce_ep<4,1><<<Bb*Ss, 256, 0, stream>>>(part, b1, nullptr, nullptr, h1);

    // 8. t2 = h1 @ W2 + b2, split-K 4-way; LN -> enc
    mfma_gemm<u16,float,0,true,false><<<dim3(Dd/128, (Bb*Ss)/128, 4), 256, 0, stream>>>(
        h1, W2T, nullptr, part, Bb*Ss, Dd, /*Kc=*/192, Ee, Ee, Dd, 1.0f,
        1, 0, 192, 0, 192, 0, MD, 0, 0);
    reduce_ep<4,0><<<Bb*Ss, 256, 0, stream>>>(part, b2, g_ff, b_ff, enc);

    // 9. logits = enc @ WpT^T + bp -> d_out (fp32), then in-place log-softmax
    mfma_gemm<u16,float,1,true,false><<<dim3(Vv/128, (Bb*Ss)/128, 1), 256, 0, stream>>>(
        enc, WpT, bp, outp, Bb*Ss, Vv, Dd, Dd, Dd, Vv, 1.0f,
        1, 0,0,0,0,0,0,0,0);
    logsoftmax_kernel<<<Bb*Ss, 256, 0, stream>>>(outp);

    // 10. cls head -> last 8 outputs (fp32)
    cls_kernel<<<Bb*2, 64, 0, stream>>>(enc, Wc, bc, outp);
}